// Round 6
// baseline (474.271 us; speedup 1.0000x reference)
//
#include <hip/hip_runtime.h>
#include <math.h>
#include <float.h>

#define NEG_SLOPE 0.2f

typedef short short8 __attribute__((ext_vector_type(8)));
typedef float f32x4  __attribute__((ext_vector_type(4)));

__device__ __forceinline__ unsigned short bf16hi(float x) {
    unsigned u = __float_as_uint(x);
    return (unsigned short)((u + 0x7FFFu + ((u >> 16) & 1u)) >> 16);
}
__device__ __forceinline__ float bf16tof(unsigned short h) {
    return __uint_as_float(((unsigned)h) << 16);
}

// K0: weights = softmax(alpha), 4 elements, single thread
__global__ void softmax4_kernel(const float* __restrict__ alpha, float* __restrict__ w) {
    float m = alpha[0];
    for (int i = 1; i < 4; i++) m = fmaxf(m, alpha[i]);
    float e[4], s = 0.f;
    for (int i = 0; i < 4; i++) { e[i] = expf(alpha[i] - m); s += e[i]; }
    for (int i = 0; i < 4; i++) w[i] = e[i] / s;
}

// K1: h = x @ W_gat  (N x 11 @ 11 x 64), plus a_src = h.att_src, a_dst = h.att_dst
__global__ __launch_bounds__(256) void gat_input_kernel(
    const float* __restrict__ x, const float* __restrict__ Wg,
    const float* __restrict__ att_src, const float* __restrict__ att_dst,
    float* __restrict__ h, float* __restrict__ a_src, float* __restrict__ a_dst, int N)
{
    __shared__ float Wl[11 * 64];
    int tid = threadIdx.x;
    for (int i = tid; i < 11 * 64; i += 256) Wl[i] = Wg[i];
    __syncthreads();
    int lane = tid & 63;
    int n = blockIdx.x * 4 + (tid >> 6);
    if (n >= N) return;
    float acc = 0.f;
    #pragma unroll
    for (int k = 0; k < 11; k++) acc += x[n * 11 + k] * Wl[k * 64 + lane];
    h[(size_t)n * 64 + lane] = acc;
    float ps = acc * att_src[lane];
    float pd = acc * att_dst[lane];
    for (int off = 32; off; off >>= 1) {
        ps += __shfl_down(ps, off, 64);
        pd += __shfl_down(pd, off, 64);
    }
    if (lane == 0) { a_src[n] = ps; a_dst[n] = pd; }
}

// ---- Bucketed CSR construction (bucket = dst >> 7, 128 dsts/bucket) ----
// bc/bcur padded to 16 ints (one cacheline) per bucket to avoid same-line atomic pileup.

__global__ __launch_bounds__(256) void bucket_count_kernel(
    const int* __restrict__ dst, int* __restrict__ bc, int E)
{
    int i = blockIdx.x * 256 + threadIdx.x;
    if (i < E) atomicAdd(&bc[(dst[i] >> 7) * 16], 1);
}

// exclusive scan of bucket counts (NBK <= 1024), single block
__global__ __launch_bounds__(1024) void bucket_scan_kernel(
    const int* __restrict__ bc, int* __restrict__ bstart, int NBK)
{
    __shared__ int s[1024];
    int t = threadIdx.x;
    int v = (t < NBK) ? bc[t * 16] : 0;
    s[t] = v; __syncthreads();
    for (int off = 1; off < 1024; off <<= 1) {
        int x = (t >= off) ? s[t - off] : 0;
        __syncthreads();
        s[t] += x;
        __syncthreads();
    }
    if (t < NBK) bstart[t] = s[t] - v;
}

// append (src,dst) to per-bucket region — bucket tail lines stay hot in L2
__global__ __launch_bounds__(256) void bucket_scatter_kernel(
    const int* __restrict__ src, const int* __restrict__ dst,
    const int* __restrict__ bstart, int* __restrict__ bcur,
    int2* __restrict__ ebuf, int E)
{
    int i = blockIdx.x * 256 + threadIdx.x;
    if (i >= E) return;
    int d = dst[i];
    int b = d >> 7;
    int pos = bstart[b] + atomicAdd(&bcur[b * 16], 1);
    ebuf[pos] = make_int2(src[i], d);
}

// one workgroup per bucket: per-dst counts in LDS -> cnt (every dst written, no memset)
__global__ __launch_bounds__(256) void bucket_cnt_kernel(
    const int2* __restrict__ ebuf, const int* __restrict__ bstart,
    const int* __restrict__ bc, int* __restrict__ cnt, int N)
{
    __shared__ int c[128];
    int b = blockIdx.x;
    int t = threadIdx.x;
    if (t < 128) c[t] = 0;
    __syncthreads();
    int beg = bstart[b], n = bc[b * 16];
    for (int j = t; j < n; j += 256)
        atomicAdd(&c[ebuf[beg + j].y & 127], 1);
    __syncthreads();
    int base = b << 7;
    if (t < 128 && base + t < N) cnt[base + t] = c[t];
}

// one workgroup per bucket: scatter src ids into the bucket's contiguous csr region
__global__ __launch_bounds__(256) void bucket_fill_kernel(
    const int2* __restrict__ ebuf, const int* __restrict__ bstart,
    const int* __restrict__ bc, const int* __restrict__ rowstart,
    int* __restrict__ csr)
{
    __shared__ int cur[128];
    int b = blockIdx.x;
    int t = threadIdx.x;
    if (t < 128) cur[t] = 0;
    __syncthreads();
    int beg = bstart[b], n = bc[b * 16];
    for (int j = t; j < n; j += 256) {
        int2 e = ebuf[beg + j];
        int p = atomicAdd(&cur[e.y & 127], 1);
        csr[rowstart[e.y] + p] = e.x;
    }
}

// ---- rowstart scan over cnt (N elements) ----
__global__ __launch_bounds__(256) void scan_reduce_kernel(
    const int* __restrict__ cnt, int* __restrict__ bsum, int N)
{
    __shared__ int s[256];
    int t = threadIdx.x;
    int base = blockIdx.x * 1024 + t * 4;
    int sum = 0;
    #pragma unroll
    for (int j = 0; j < 4; j++) { int idx = base + j; if (idx < N) sum += cnt[idx]; }
    s[t] = sum; __syncthreads();
    for (int off = 128; off; off >>= 1) {
        if (t < off) s[t] += s[t + off];
        __syncthreads();
    }
    if (t == 0) bsum[blockIdx.x] = s[0];
}

__global__ __launch_bounds__(256) void scan_spine_kernel(
    const int* __restrict__ bsum, int* __restrict__ boff, int NB)
{
    __shared__ int s[256];
    int t = threadIdx.x;
    int v = (t < NB) ? bsum[t] : 0;
    s[t] = v; __syncthreads();
    for (int off = 1; off < 256; off <<= 1) {
        int x = (t >= off) ? s[t - off] : 0;
        __syncthreads();
        s[t] += x;
        __syncthreads();
    }
    if (t < NB) boff[t] = s[t] - v;
}

__global__ __launch_bounds__(256) void scan_apply_kernel(
    const int* __restrict__ cnt, const int* __restrict__ boff,
    int* __restrict__ rowstart, int N)
{
    __shared__ int s[256];
    int t = threadIdx.x;
    int base = blockIdx.x * 1024;
    int v[4]; int sum = 0;
    #pragma unroll
    for (int j = 0; j < 4; j++) {
        int idx = base + t * 4 + j;
        v[j] = (idx < N) ? cnt[idx] : 0;
        sum += v[j];
    }
    s[t] = sum; __syncthreads();
    for (int off = 1; off < 256; off <<= 1) {
        int x = (t >= off) ? s[t - off] : 0;
        __syncthreads();
        s[t] += x;
        __syncthreads();
    }
    int ex = s[t] - sum + boff[blockIdx.x];
    #pragma unroll
    for (int j = 0; j < 4; j++) {
        int idx = base + t * 4 + j;
        if (idx < N) rowstart[idx] = ex;
        ex += v[j];
    }
}

// K2: GAT gather — wave per dst node, online softmax, float4 row gathers
__global__ __launch_bounds__(256) void gat_gather_kernel(
    const float* __restrict__ h, const float* __restrict__ a_src,
    const float* __restrict__ a_dst, const float* __restrict__ bg,
    const int* __restrict__ rowstart, const int* __restrict__ cnt,
    const int* __restrict__ csr, const float* __restrict__ wsm,
    float* __restrict__ hgat, float* __restrict__ outD, int N)
{
    const float4* __restrict__ h4 = (const float4*)h;
    int d = blockIdx.x * 4 + (threadIdx.x >> 6);
    int lane = threadIdx.x & 63;
    if (d >= N) return;
    int grp = lane >> 4;
    int sub = lane & 15;
    float ad = a_dst[d];
    int beg = rowstart[d], deg = cnt[d];
    float a0 = a_src[d] + ad;
    float m = a0 > 0.f ? a0 : NEG_SLOPE * a0;
    float l = 1.0f;
    float4 accA = make_float4(0.f, 0.f, 0.f, 0.f);
    float4 accB = make_float4(0.f, 0.f, 0.f, 0.f);
    if (grp == 0) accA = h4[(size_t)d * 16 + sub];
    for (int base = 0; base < deg; base += 64) {
        int eidx = base + lane;
        bool valid = eidx < deg;
        int sid = valid ? csr[beg + eidx] : 0;
        float aa = valid ? (a_src[sid] + ad) : 0.f;
        float lg = aa > 0.f ? aa : NEG_SLOPE * aa;
        if (!valid) lg = -FLT_MAX;
        float cm = lg;
        for (int off = 32; off; off >>= 1) cm = fmaxf(cm, __shfl_xor(cm, off, 64));
        float nm = fmaxf(m, cm);
        float scale = expf(m - nm);
        accA.x *= scale; accA.y *= scale; accA.z *= scale; accA.w *= scale;
        accB.x *= scale; accB.y *= scale; accB.z *= scale; accB.w *= scale;
        l *= scale; m = nm;
        float w = valid ? expf(lg - m) : 0.f;
        float ws = w;
        for (int off = 32; off; off >>= 1) ws += __shfl_xor(ws, off, 64);
        l += ws;
        int nvalid = deg - base; if (nvalid > 64) nvalid = 64;
        for (int j = 0; j < nvalid; j += 16) {
            int e0 = j + grp,      e1 = j + 4 + grp;
            int e2 = j + 8 + grp,  e3 = j + 12 + grp;
            int   i0 = __shfl(sid, e0, 64); float w0 = __shfl(w, e0, 64);
            int   i1 = __shfl(sid, e1, 64); float w1 = __shfl(w, e1, 64);
            int   i2 = __shfl(sid, e2, 64); float w2 = __shfl(w, e2, 64);
            int   i3 = __shfl(sid, e3, 64); float w3 = __shfl(w, e3, 64);
            float4 v0 = h4[(size_t)i0 * 16 + sub];
            float4 v1 = h4[(size_t)i1 * 16 + sub];
            float4 v2 = h4[(size_t)i2 * 16 + sub];
            float4 v3 = h4[(size_t)i3 * 16 + sub];
            accA.x += w0 * v0.x + w1 * v1.x; accB.x += w2 * v2.x + w3 * v3.x;
            accA.y += w0 * v0.y + w1 * v1.y; accB.y += w2 * v2.y + w3 * v3.y;
            accA.z += w0 * v0.z + w1 * v1.z; accB.z += w2 * v2.z + w3 * v3.z;
            accA.w += w0 * v0.w + w1 * v1.w; accB.w += w2 * v2.w + w3 * v3.w;
        }
    }
    float4 acc;
    acc.x = accA.x + accB.x; acc.y = accA.y + accB.y;
    acc.z = accA.z + accB.z; acc.w = accA.w + accB.w;
    #pragma unroll
    for (int off = 16; off <= 32; off <<= 1) {
        acc.x += __shfl_xor(acc.x, off, 64);
        acc.y += __shfl_xor(acc.y, off, 64);
        acc.z += __shfl_xor(acc.z, off, 64);
        acc.w += __shfl_xor(acc.w, off, 64);
    }
    float inv = 1.0f / (l + 1e-16f);
    const float4* bg4 = (const float4*)bg;
    float4 bb = bg4[sub];
    float4 out;
    out.x = acc.x * inv + bb.x; out.y = acc.y * inv + bb.y;
    out.z = acc.z * inv + bb.z; out.w = acc.w * inv + bb.w;
    size_t idx = (size_t)d * 16 + sub;
    if (grp == 0) ((float4*)hgat)[idx] = out;
    if (grp == 1) {
        float w0 = wsm[0];
        float4 o; o.x = w0 * out.x; o.y = w0 * out.y; o.z = w0 * out.z; o.w = w0 * out.w;
        ((float4*)outD)[idx] = o;
    }
}

// K5: convert [Wl|Wr] (64x128 fp32, k-major) into MFMA b-frag layout, bf16 hi/lo.
__global__ __launch_bounds__(256) void wprep_kernel(
    const float* __restrict__ Wl, const float* __restrict__ Wr,
    unsigned short* __restrict__ Whi, unsigned short* __restrict__ Wlo)
{
    int idx = blockIdx.x * 256 + threadIdx.x;   // 0..1023
    if (idx >= 1024) return;
    int kc = idx >> 9, rem = idx & 511;
    int t = rem >> 6, lane = rem & 63;
    int quad = lane >> 4, col16 = lane & 15;
    int c = t * 16 + col16;
    #pragma unroll
    for (int j = 0; j < 8; j++) {
        int k = kc * 32 + quad * 8 + j;
        float w = (c < 64) ? Wl[k * 64 + c] : Wr[k * 64 + (c - 64)];
        unsigned short hi = bf16hi(w);
        unsigned short lo = bf16hi(w - bf16tof(hi));
        Whi[(size_t)idx * 8 + j] = hi;
        Wlo[(size_t)idx * 8 + j] = lo;
    }
}

// K6: dense GEMM [P|Q] = hin @ [Wl|Wr] (+b on Q half) via mfma 16x16x32 bf16x3.
__global__ __launch_bounds__(256) void sage_gemm_kernel(
    const float* __restrict__ hin,
    const unsigned short* __restrict__ Whi, const unsigned short* __restrict__ Wlo,
    const float* __restrict__ bvec,
    float* __restrict__ P, float* __restrict__ Q, int N)
{
    int wave = threadIdx.x >> 6, lane = threadIdx.x & 63;
    int base = blockIdx.x * 64 + wave * 16;
    if (base >= N) return;
    int quad = lane >> 4, col16 = lane & 15;
    int m = base + col16;
    int mc = m < N ? m : N - 1;
    f32x4 acc[8];
    #pragma unroll
    for (int t = 0; t < 8; t++) acc[t] = (f32x4){0.f, 0.f, 0.f, 0.f};
    #pragma unroll
    for (int kc = 0; kc < 2; kc++) {
        const float* ap = hin + (size_t)mc * 64 + kc * 32 + quad * 8;
        float4 va = *(const float4*)ap;
        float4 vb = *(const float4*)(ap + 4);
        float av[8] = {va.x, va.y, va.z, va.w, vb.x, vb.y, vb.z, vb.w};
        short8 ahi, alo;
        #pragma unroll
        for (int j = 0; j < 8; j++) {
            unsigned short hh = bf16hi(av[j]);
            ahi[j] = (short)hh;
            alo[j] = (short)bf16hi(av[j] - bf16tof(hh));
        }
        #pragma unroll
        for (int t = 0; t < 8; t++) {
            size_t off = ((size_t)(kc * 8 + t) * 64 + lane) * 8;
            short8 bhi = *(const short8*)(Whi + off);
            short8 blo = *(const short8*)(Wlo + off);
            acc[t] = __builtin_amdgcn_mfma_f32_16x16x32_bf16(ahi, bhi, acc[t], 0, 0, 0);
            acc[t] = __builtin_amdgcn_mfma_f32_16x16x32_bf16(alo, bhi, acc[t], 0, 0, 0);
            acc[t] = __builtin_amdgcn_mfma_f32_16x16x32_bf16(ahi, blo, acc[t], 0, 0, 0);
        }
    }
    #pragma unroll
    for (int t = 0; t < 8; t++) {
        #pragma unroll
        for (int r = 0; r < 4; r++) {
            int node = base + quad * 4 + r;
            if (node < N) {
                float v = acc[t][r];
                if (t < 4) {
                    P[(size_t)node * 64 + t * 16 + col16] = v;
                } else {
                    int c = (t - 4) * 16 + col16;
                    Q[(size_t)node * 64 + c] = v + bvec[c];
                }
            }
        }
    }
}

// K7: SAGE post — h' = mean_nbr(P) + Q[d]; outD += w*h'; optional hout store.
__global__ __launch_bounds__(256) void sage_post_kernel(
    const float* __restrict__ P, const float* __restrict__ Q,
    const int* __restrict__ rowstart, const int* __restrict__ cnt,
    const int* __restrict__ csr, const float* __restrict__ wsm, int widx,
    float* __restrict__ hout, float* __restrict__ outD, int N)
{
    const float4* __restrict__ P4 = (const float4*)P;
    int d = blockIdx.x * 4 + (threadIdx.x >> 6);
    int lane = threadIdx.x & 63;
    if (d >= N) return;
    int grp = lane >> 4, sub = lane & 15;
    int beg = rowstart[d], deg = cnt[d];
    float4 s0 = make_float4(0.f,0.f,0.f,0.f), s1 = s0, s2 = s0, s3 = s0;
    for (int base = 0; base < deg; base += 64) {
        int nv = deg - base; if (nv > 64) nv = 64;
        int sid = (lane < nv) ? csr[beg + base + lane] : 0;
        for (int j = 0; j < nv; j += 16) {
            int e0 = j + grp,     e1 = j + 4 + grp;
            int e2 = j + 8 + grp, e3 = j + 12 + grp;
            int i0 = __shfl(sid, e0, 64);
            int i1 = __shfl(sid, e1, 64);
            int i2 = __shfl(sid, e2, 64);
            int i3 = __shfl(sid, e3, 64);
            if (e0 < nv) { float4 v = P4[(size_t)i0 * 16 + sub]; s0.x += v.x; s0.y += v.y; s0.z += v.z; s0.w += v.w; }
            if (e1 < nv) { float4 v = P4[(size_t)i1 * 16 + sub]; s1.x += v.x; s1.y += v.y; s1.z += v.z; s1.w += v.w; }
            if (e2 < nv) { float4 v = P4[(size_t)i2 * 16 + sub]; s2.x += v.x; s2.y += v.y; s2.z += v.z; s2.w += v.w; }
            if (e3 < nv) { float4 v = P4[(size_t)i3 * 16 + sub]; s3.x += v.x; s3.y += v.y; s3.z += v.z; s3.w += v.w; }
        }
    }
    float4 sv;
    sv.x = (s0.x + s1.x) + (s2.x + s3.x);
    sv.y = (s0.y + s1.y) + (s2.y + s3.y);
    sv.z = (s0.z + s1.z) + (s2.z + s3.z);
    sv.w = (s0.w + s1.w) + (s2.w + s3.w);
    #pragma unroll
    for (int off = 16; off <= 32; off <<= 1) {
        sv.x += __shfl_xor(sv.x, off, 64);
        sv.y += __shfl_xor(sv.y, off, 64);
        sv.z += __shfl_xor(sv.z, off, 64);
        sv.w += __shfl_xor(sv.w, off, 64);
    }
    float invd = 1.0f / fmaxf((float)deg, 1.0f);
    size_t idx = (size_t)d * 16 + sub;
    float4 q4 = ((const float4*)Q)[idx];
    float4 o;
    o.x = sv.x * invd + q4.x; o.y = sv.y * invd + q4.y;
    o.z = sv.z * invd + q4.z; o.w = sv.w * invd + q4.w;
    if (hout && grp == 0) ((float4*)hout)[idx] = o;
    if (grp == 1) {
        float w = wsm[widx];
        float4 dd = ((float4*)outD)[idx];
        dd.x += w * o.x; dd.y += w * o.y; dd.z += w * o.z; dd.w += w * o.w;
        ((float4*)outD)[idx] = dd;
    }
}

// K8: 16 lanes per label-edge (float4 rows): out[e] = dot(outf[a], outf[b])
__global__ __launch_bounds__(256) void link_pred_kernel(
    const int* __restrict__ eli, const float* __restrict__ outf,
    float* __restrict__ out, int EL)
{
    const float4* __restrict__ o4 = (const float4*)outf;
    int e = blockIdx.x * 16 + (threadIdx.x >> 4);
    int sub = threadIdx.x & 15;
    if (e >= EL) return;
    int a = eli[e], b = eli[EL + e];
    float4 pa = o4[(size_t)a * 16 + sub];
    float4 pb = o4[(size_t)b * 16 + sub];
    float p = pa.x * pb.x + pa.y * pb.y + pa.z * pb.z + pa.w * pb.w;
    for (int off = 8; off; off >>= 1) p += __shfl_xor(p, off, 64);
    if (sub == 0) out[e] = p;
}

extern "C" void kernel_launch(void* const* d_in, const int* in_sizes, int n_in,
                              void* d_out, int out_size, void* d_ws, size_t ws_size,
                              hipStream_t stream)
{
    const float* x      = (const float*)d_in[0];
    const int*   ei     = (const int*)d_in[1];
    const int*   eli    = (const int*)d_in[2];
    const float* Wg     = (const float*)d_in[3];
    const float* att_s  = (const float*)d_in[4];
    const float* att_d  = (const float*)d_in[5];
    const float* bg     = (const float*)d_in[6];
    const float* W1l    = (const float*)d_in[7];
    const float* W1r    = (const float*)d_in[8];
    const float* b1     = (const float*)d_in[9];
    const float* W2l    = (const float*)d_in[10];
    const float* W2r    = (const float*)d_in[11];
    const float* b2     = (const float*)d_in[12];
    const float* alpha  = (const float*)d_in[13];

    const int N  = in_sizes[0] / 11;
    const int E  = in_sizes[1] / 2;
    const int EL = in_sizes[2] / 2;
    const int NBK = (N + 127) >> 7;   // buckets of 128 dsts (782 for N=100k, <=1024)

    const int* src = ei;
    const int* dst = ei + E;

    // workspace layout
    float* A        = (float*)d_ws;              // N*64: h -> P1 -> P2
    float* B        = A + (size_t)N * 64;        // N*64: h_gat -> Q1/h1 -> Q2
    float* D        = B + (size_t)N * 64;        // N*64: ebuf (CSR build) then output accum
    float* a_src    = D + (size_t)N * 64;        // N
    float* a_dst    = a_src + N;                 // N
    int*   cnt      = (int*)(a_dst + N);         // N
    int*   rowstart = cnt + N;                   // N
    int*   bsum     = rowstart + N;              // 256
    int*   boff     = bsum + 256;                // 256
    int*   bc       = boff + 256;                // NBK*16 (padded counters)
    int*   bcur     = bc + NBK * 16;             // NBK*16
    int*   bstart   = bcur + NBK * 16;           // NBK
    int*   csr      = bstart + NBK;              // E
    unsigned short* wf = (unsigned short*)(csr + E);  // 4 x 8192 ushorts
    unsigned short* W1hi = wf;
    unsigned short* W1lo = wf + 8192;
    unsigned short* W2hi = wf + 16384;
    unsigned short* W2lo = wf + 24576;
    float* wsm      = (float*)(wf + 32768);      // 4
    int2*  ebuf     = (int2*)D;                  // E pairs (8 MB) — dead before gat_gather writes D

    hipMemsetAsync(bc,   0, (size_t)NBK * 16 * sizeof(int), stream);
    hipMemsetAsync(bcur, 0, (size_t)NBK * 16 * sizeof(int), stream);

    softmax4_kernel<<<1, 1, 0, stream>>>(alpha, wsm);
    wprep_kernel<<<4, 256, 0, stream>>>(W1l, W1r, W1hi, W1lo);
    wprep_kernel<<<4, 256, 0, stream>>>(W2l, W2r, W2hi, W2lo);

    gat_input_kernel<<<(N + 3) / 4, 256, 0, stream>>>(x, Wg, att_s, att_d, A, a_src, a_dst, N);

    // Bucketed CSR build
    bucket_count_kernel<<<(E + 255) / 256, 256, 0, stream>>>(dst, bc, E);
    bucket_scan_kernel<<<1, 1024, 0, stream>>>(bc, bstart, NBK);
    bucket_scatter_kernel<<<(E + 255) / 256, 256, 0, stream>>>(src, dst, bstart, bcur, ebuf, E);
    bucket_cnt_kernel<<<NBK, 256, 0, stream>>>(ebuf, bstart, bc, cnt, N);
    int NB = (N + 1023) / 1024;
    scan_reduce_kernel<<<NB, 256, 0, stream>>>(cnt, bsum, N);
    scan_spine_kernel<<<1, 256, 0, stream>>>(bsum, boff, NB);
    scan_apply_kernel<<<NB, 256, 0, stream>>>(cnt, boff, rowstart, N);
    bucket_fill_kernel<<<NBK, 256, 0, stream>>>(ebuf, bstart, bc, rowstart, csr);

    // GAT: read h (A) -> h_gat (B), D = w0*h_gat  (overwrites ebuf — now dead)
    gat_gather_kernel<<<(N + 3) / 4, 256, 0, stream>>>(A, a_src, a_dst, bg,
                                                       rowstart, cnt, csr, wsm, B, D, N);

    // SAGE1: GEMM reads B(hgat): P1 -> A, Q1 -> B (in-place). post: h1 -> B, D += w2*h1
    sage_gemm_kernel<<<(N + 63) / 64, 256, 0, stream>>>(B, W1hi, W1lo, b1, A, B, N);
    sage_post_kernel<<<(N + 3) / 4, 256, 0, stream>>>(A, B, rowstart, cnt, csr, wsm, 2, B, D, N);

    // SAGE2: GEMM reads B(h1): P2 -> A, Q2 -> B (in-place). post: D += w3*h2
    sage_gemm_kernel<<<(N + 63) / 64, 256, 0, stream>>>(B, W2hi, W2lo, b2, A, B, N);
    sage_post_kernel<<<(N + 3) / 4, 256, 0, stream>>>(A, B, rowstart, cnt, csr, wsm, 3, nullptr, D, N);

    link_pred_kernel<<<(EL + 15) / 16, 256, 0, stream>>>(eli, D, (float*)d_out, EL);
}

// Round 7
// 454.059 us; speedup vs baseline: 1.0445x; 1.0445x over previous
//
#include <hip/hip_runtime.h>
#include <math.h>
#include <float.h>

#define NEG_SLOPE 0.2f

typedef short short8 __attribute__((ext_vector_type(8)));
typedef float f32x4  __attribute__((ext_vector_type(4)));

__device__ __forceinline__ unsigned short bf16hi(float x) {
    unsigned u = __float_as_uint(x);
    return (unsigned short)((u + 0x7FFFu + ((u >> 16) & 1u)) >> 16);
}
__device__ __forceinline__ float bf16tof(unsigned short h) {
    return __uint_as_float(((unsigned)h) << 16);
}

// K1: h = x @ W_gat  (N x 11 @ 11 x 64), plus a_src = h.att_src, a_dst = h.att_dst
__global__ __launch_bounds__(256) void gat_input_kernel(
    const float* __restrict__ x, const float* __restrict__ Wg,
    const float* __restrict__ att_src, const float* __restrict__ att_dst,
    float* __restrict__ h, float* __restrict__ a_src, float* __restrict__ a_dst, int N)
{
    __shared__ float Wl[11 * 64];
    int tid = threadIdx.x;
    for (int i = tid; i < 11 * 64; i += 256) Wl[i] = Wg[i];
    __syncthreads();
    int lane = tid & 63;
    int n = blockIdx.x * 4 + (tid >> 6);
    if (n >= N) return;
    float acc = 0.f;
    #pragma unroll
    for (int k = 0; k < 11; k++) acc += x[n * 11 + k] * Wl[k * 64 + lane];
    h[(size_t)n * 64 + lane] = acc;
    float ps = acc * att_src[lane];
    float pd = acc * att_dst[lane];
    for (int off = 32; off; off >>= 1) {
        ps += __shfl_down(ps, off, 64);
        pd += __shfl_down(pd, off, 64);
    }
    if (lane == 0) { a_src[n] = ps; a_dst[n] = pd; }
}

// ---- Bucketed CSR construction (bucket = dst >> 7, 128 dsts/bucket) ----

__global__ __launch_bounds__(256) void bucket_count_kernel(
    const int* __restrict__ dst, int* __restrict__ bc, int E)
{
    int i = blockIdx.x * 256 + threadIdx.x;
    if (i < E) atomicAdd(&bc[(dst[i] >> 7) * 16], 1);
}

// exclusive scan of bucket counts (NBK <= 1024), single block
__global__ __launch_bounds__(1024) void bucket_scan_kernel(
    const int* __restrict__ bc, int* __restrict__ bstart, int NBK)
{
    __shared__ int s[1024];
    int t = threadIdx.x;
    int v = (t < NBK) ? bc[t * 16] : 0;
    s[t] = v; __syncthreads();
    for (int off = 1; off < 1024; off <<= 1) {
        int x = (t >= off) ? s[t - off] : 0;
        __syncthreads();
        s[t] += x;
        __syncthreads();
    }
    if (t < NBK) bstart[t] = s[t] - v;
}

// append (src,dst) to per-bucket region
__global__ __launch_bounds__(256) void bucket_scatter_kernel(
    const int* __restrict__ src, const int* __restrict__ dst,
    const int* __restrict__ bstart, int* __restrict__ bcur,
    int2* __restrict__ ebuf, int E)
{
    int i = blockIdx.x * 256 + threadIdx.x;
    if (i >= E) return;
    int d = dst[i];
    int b = d >> 7;
    int pos = bstart[b] + atomicAdd(&bcur[b * 16], 1);
    ebuf[pos] = make_int2(src[i], d);
}

// one workgroup per bucket: LDS per-dst counts -> LDS scan -> cnt/rowstart -> scatter csr
__global__ __launch_bounds__(256) void bucket_build_kernel(
    const int2* __restrict__ ebuf, const int* __restrict__ bstart,
    const int* __restrict__ bc, int* __restrict__ cnt, int* __restrict__ rowstart,
    int* __restrict__ csr, int N)
{
    __shared__ int c[128];
    __shared__ int rs[128];   // exclusive prefix within bucket
    __shared__ int cur[128];
    int b = blockIdx.x, t = threadIdx.x;
    if (t < 128) { c[t] = 0; cur[t] = 0; }
    __syncthreads();
    int beg = bstart[b], n = bc[b * 16];
    for (int j = t; j < n; j += 256)
        atomicAdd(&c[ebuf[beg + j].y & 127], 1);
    __syncthreads();
    // Hillis-Steele inclusive scan over 128 counts
    int myc = (t < 128) ? c[t] : 0;
    if (t < 128) rs[t] = myc;
    __syncthreads();
    for (int off = 1; off < 128; off <<= 1) {
        int v = (t < 128 && t >= off) ? rs[t - off] : 0;
        __syncthreads();
        if (t < 128) rs[t] += v;
        __syncthreads();
    }
    int ex = (t < 128) ? (rs[t] - myc) : 0;
    __syncthreads();
    if (t < 128) rs[t] = ex;            // now exclusive
    int base = b << 7;
    if (t < 128 && base + t < N) {
        cnt[base + t] = myc;
        rowstart[base + t] = beg + ex;
    }
    __syncthreads();
    for (int j = t; j < n; j += 256) {
        int2 e = ebuf[beg + j];
        int d = e.y & 127;
        int p = atomicAdd(&cur[d], 1);
        csr[beg + rs[d] + p] = e.x;
    }
}

// K2: GAT gather — wave per dst node, plain exp softmax (shift-invariant, logits bounded),
// float4 row gathers: 16 lanes per row, 4 edges per load instruction.
__global__ __launch_bounds__(256) void gat_gather_kernel(
    const float* __restrict__ h, const float* __restrict__ a_src,
    const float* __restrict__ a_dst, const float* __restrict__ bg,
    const int* __restrict__ rowstart, const int* __restrict__ cnt,
    const int* __restrict__ csr, const float* __restrict__ wsm,
    float* __restrict__ hgat, float* __restrict__ outD, int N)
{
    const float4* __restrict__ h4 = (const float4*)h;
    int d = blockIdx.x * 4 + (threadIdx.x >> 6);
    int lane = threadIdx.x & 63;
    if (d >= N) return;
    int grp = lane >> 4;
    int sub = lane & 15;
    float ad = a_dst[d];
    int beg = rowstart[d], deg = cnt[d];
    float a0 = a_src[d] + ad;
    float lg0 = a0 > 0.f ? a0 : NEG_SLOPE * a0;
    float w_self = expf(lg0);
    float l_lane = 0.f;
    float4 accA = make_float4(0.f, 0.f, 0.f, 0.f);
    float4 accB = make_float4(0.f, 0.f, 0.f, 0.f);
    if (grp == 0) {
        float4 hv = h4[(size_t)d * 16 + sub];
        accA.x = w_self * hv.x; accA.y = w_self * hv.y;
        accA.z = w_self * hv.z; accA.w = w_self * hv.w;
    }
    for (int base = 0; base < deg; base += 64) {
        int eidx = base + lane;
        bool valid = eidx < deg;
        int sid = valid ? csr[beg + eidx] : 0;
        float aa = a_src[sid] + ad;
        float lg = aa > 0.f ? aa : NEG_SLOPE * aa;
        float w = valid ? expf(lg) : 0.f;
        l_lane += w;
        int nvalid = deg - base; if (nvalid > 64) nvalid = 64;
        for (int j = 0; j < nvalid; j += 16) {
            int e0 = j + grp,      e1 = j + 4 + grp;
            int e2 = j + 8 + grp,  e3 = j + 12 + grp;
            int   i0 = __shfl(sid, e0, 64); float w0 = __shfl(w, e0, 64);
            int   i1 = __shfl(sid, e1, 64); float w1 = __shfl(w, e1, 64);
            int   i2 = __shfl(sid, e2, 64); float w2 = __shfl(w, e2, 64);
            int   i3 = __shfl(sid, e3, 64); float w3 = __shfl(w, e3, 64);
            float4 v0 = h4[(size_t)i0 * 16 + sub];
            float4 v1 = h4[(size_t)i1 * 16 + sub];
            float4 v2 = h4[(size_t)i2 * 16 + sub];
            float4 v3 = h4[(size_t)i3 * 16 + sub];
            accA.x += w0 * v0.x + w1 * v1.x; accB.x += w2 * v2.x + w3 * v3.x;
            accA.y += w0 * v0.y + w1 * v1.y; accB.y += w2 * v2.y + w3 * v3.y;
            accA.z += w0 * v0.z + w1 * v1.z; accB.z += w2 * v2.z + w3 * v3.z;
            accA.w += w0 * v0.w + w1 * v1.w; accB.w += w2 * v2.w + w3 * v3.w;
        }
    }
    // denominator: reduce l_lane across all 64 lanes, add self weight
    for (int off = 32; off; off >>= 1) l_lane += __shfl_xor(l_lane, off, 64);
    float l = l_lane + w_self;
    float4 acc;
    acc.x = accA.x + accB.x; acc.y = accA.y + accB.y;
    acc.z = accA.z + accB.z; acc.w = accA.w + accB.w;
    #pragma unroll
    for (int off = 16; off <= 32; off <<= 1) {
        acc.x += __shfl_xor(acc.x, off, 64);
        acc.y += __shfl_xor(acc.y, off, 64);
        acc.z += __shfl_xor(acc.z, off, 64);
        acc.w += __shfl_xor(acc.w, off, 64);
    }
    float inv = 1.0f / (l + 1e-16f);
    const float4* bg4 = (const float4*)bg;
    float4 bb = bg4[sub];
    float4 out;
    out.x = acc.x * inv + bb.x; out.y = acc.y * inv + bb.y;
    out.z = acc.z * inv + bb.z; out.w = acc.w * inv + bb.w;
    size_t idx = (size_t)d * 16 + sub;
    if (grp == 0) ((float4*)hgat)[idx] = out;
    if (grp == 1) {
        float w0 = wsm[0];
        float4 o; o.x = w0 * out.x; o.y = w0 * out.y; o.z = w0 * out.z; o.w = w0 * out.w;
        ((float4*)outD)[idx] = o;
    }
}

// K5: both weight pairs -> MFMA b-frag layout (bf16 hi/lo); block 0 also does softmax(alpha).
// grid = 8 blocks: blocks 0-3 -> W1, 4-7 -> W2.
__global__ __launch_bounds__(256) void wprep2_kernel(
    const float* __restrict__ W1l, const float* __restrict__ W1r,
    const float* __restrict__ W2l, const float* __restrict__ W2r,
    unsigned short* __restrict__ W1hi, unsigned short* __restrict__ W1lo,
    unsigned short* __restrict__ W2hi, unsigned short* __restrict__ W2lo,
    const float* __restrict__ alpha, float* __restrict__ wsm)
{
    if (blockIdx.x == 0 && threadIdx.x == 0) {
        float m = alpha[0];
        for (int i = 1; i < 4; i++) m = fmaxf(m, alpha[i]);
        float e[4], s = 0.f;
        for (int i = 0; i < 4; i++) { e[i] = expf(alpha[i] - m); s += e[i]; }
        for (int i = 0; i < 4; i++) wsm[i] = e[i] / s;
    }
    int which = blockIdx.x >> 2;
    const float* Wl = which ? W2l : W1l;
    const float* Wr = which ? W2r : W1r;
    unsigned short* Whi = which ? W2hi : W1hi;
    unsigned short* Wlo = which ? W2lo : W1lo;
    int idx = (blockIdx.x & 3) * 256 + threadIdx.x;   // 0..1023
    int kc = idx >> 9, rem = idx & 511;
    int t = rem >> 6, lane = rem & 63;
    int quad = lane >> 4, col16 = lane & 15;
    int c = t * 16 + col16;
    #pragma unroll
    for (int j = 0; j < 8; j++) {
        int k = kc * 32 + quad * 8 + j;
        float w = (c < 64) ? Wl[k * 64 + c] : Wr[k * 64 + (c - 64)];
        unsigned short hi = bf16hi(w);
        unsigned short lo = bf16hi(w - bf16tof(hi));
        Whi[(size_t)idx * 8 + j] = hi;
        Wlo[(size_t)idx * 8 + j] = lo;
    }
}

// K6: dense GEMM [P|Q] = hin @ [Wl|Wr] (+b on Q half) via mfma 16x16x32 bf16x3.
__global__ __launch_bounds__(256) void sage_gemm_kernel(
    const float* __restrict__ hin,
    const unsigned short* __restrict__ Whi, const unsigned short* __restrict__ Wlo,
    const float* __restrict__ bvec,
    float* __restrict__ P, float* __restrict__ Q, int N)
{
    int wave = threadIdx.x >> 6, lane = threadIdx.x & 63;
    int base = blockIdx.x * 64 + wave * 16;
    if (base >= N) return;
    int quad = lane >> 4, col16 = lane & 15;
    int m = base + col16;
    int mc = m < N ? m : N - 1;
    f32x4 acc[8];
    #pragma unroll
    for (int t = 0; t < 8; t++) acc[t] = (f32x4){0.f, 0.f, 0.f, 0.f};
    #pragma unroll
    for (int kc = 0; kc < 2; kc++) {
        const float* ap = hin + (size_t)mc * 64 + kc * 32 + quad * 8;
        float4 va = *(const float4*)ap;
        float4 vb = *(const float4*)(ap + 4);
        float av[8] = {va.x, va.y, va.z, va.w, vb.x, vb.y, vb.z, vb.w};
        short8 ahi, alo;
        #pragma unroll
        for (int j = 0; j < 8; j++) {
            unsigned short hh = bf16hi(av[j]);
            ahi[j] = (short)hh;
            alo[j] = (short)bf16hi(av[j] - bf16tof(hh));
        }
        #pragma unroll
        for (int t = 0; t < 8; t++) {
            size_t off = ((size_t)(kc * 8 + t) * 64 + lane) * 8;
            short8 bhi = *(const short8*)(Whi + off);
            short8 blo = *(const short8*)(Wlo + off);
            acc[t] = __builtin_amdgcn_mfma_f32_16x16x32_bf16(ahi, bhi, acc[t], 0, 0, 0);
            acc[t] = __builtin_amdgcn_mfma_f32_16x16x32_bf16(alo, bhi, acc[t], 0, 0, 0);
            acc[t] = __builtin_amdgcn_mfma_f32_16x16x32_bf16(ahi, blo, acc[t], 0, 0, 0);
        }
    }
    #pragma unroll
    for (int t = 0; t < 8; t++) {
        #pragma unroll
        for (int r = 0; r < 4; r++) {
            int node = base + quad * 4 + r;
            if (node < N) {
                float v = acc[t][r];
                if (t < 4) {
                    P[(size_t)node * 64 + t * 16 + col16] = v;
                } else {
                    int c = (t - 4) * 16 + col16;
                    Q[(size_t)node * 64 + c] = v + bvec[c];
                }
            }
        }
    }
}

// K7: SAGE post — h' = mean_nbr(P) + Q[d]; outD += w*h'; optional hout store.
__global__ __launch_bounds__(256) void sage_post_kernel(
    const float* __restrict__ P, const float* __restrict__ Q,
    const int* __restrict__ rowstart, const int* __restrict__ cnt,
    const int* __restrict__ csr, const float* __restrict__ wsm, int widx,
    float* __restrict__ hout, float* __restrict__ outD, int N)
{
    const float4* __restrict__ P4 = (const float4*)P;
    int d = blockIdx.x * 4 + (threadIdx.x >> 6);
    int lane = threadIdx.x & 63;
    if (d >= N) return;
    int grp = lane >> 4, sub = lane & 15;
    int beg = rowstart[d], deg = cnt[d];
    float4 s0 = make_float4(0.f,0.f,0.f,0.f), s1 = s0, s2 = s0, s3 = s0;
    for (int base = 0; base < deg; base += 64) {
        int nv = deg - base; if (nv > 64) nv = 64;
        int sid = (lane < nv) ? csr[beg + base + lane] : 0;
        for (int j = 0; j < nv; j += 16) {
            int e0 = j + grp,     e1 = j + 4 + grp;
            int e2 = j + 8 + grp, e3 = j + 12 + grp;
            int i0 = __shfl(sid, e0, 64);
            int i1 = __shfl(sid, e1, 64);
            int i2 = __shfl(sid, e2, 64);
            int i3 = __shfl(sid, e3, 64);
            if (e0 < nv) { float4 v = P4[(size_t)i0 * 16 + sub]; s0.x += v.x; s0.y += v.y; s0.z += v.z; s0.w += v.w; }
            if (e1 < nv) { float4 v = P4[(size_t)i1 * 16 + sub]; s1.x += v.x; s1.y += v.y; s1.z += v.z; s1.w += v.w; }
            if (e2 < nv) { float4 v = P4[(size_t)i2 * 16 + sub]; s2.x += v.x; s2.y += v.y; s2.z += v.z; s2.w += v.w; }
            if (e3 < nv) { float4 v = P4[(size_t)i3 * 16 + sub]; s3.x += v.x; s3.y += v.y; s3.z += v.z; s3.w += v.w; }
        }
    }
    float4 sv;
    sv.x = (s0.x + s1.x) + (s2.x + s3.x);
    sv.y = (s0.y + s1.y) + (s2.y + s3.y);
    sv.z = (s0.z + s1.z) + (s2.z + s3.z);
    sv.w = (s0.w + s1.w) + (s2.w + s3.w);
    #pragma unroll
    for (int off = 16; off <= 32; off <<= 1) {
        sv.x += __shfl_xor(sv.x, off, 64);
        sv.y += __shfl_xor(sv.y, off, 64);
        sv.z += __shfl_xor(sv.z, off, 64);
        sv.w += __shfl_xor(sv.w, off, 64);
    }
    float invd = 1.0f / fmaxf((float)deg, 1.0f);
    size_t idx = (size_t)d * 16 + sub;
    float4 q4 = ((const float4*)Q)[idx];
    float4 o;
    o.x = sv.x * invd + q4.x; o.y = sv.y * invd + q4.y;
    o.z = sv.z * invd + q4.z; o.w = sv.w * invd + q4.w;
    if (hout && grp == 0) ((float4*)hout)[idx] = o;
    if (grp == 1) {
        float w = wsm[widx];
        float4 dd = ((float4*)outD)[idx];
        dd.x += w * o.x; dd.y += w * o.y; dd.z += w * o.z; dd.w += w * o.w;
        ((float4*)outD)[idx] = dd;
    }
}

// K8: 16 lanes per label-edge (float4 rows): out[e] = dot(outf[a], outf[b])
__global__ __launch_bounds__(256) void link_pred_kernel(
    const int* __restrict__ eli, const float* __restrict__ outf,
    float* __restrict__ out, int EL)
{
    const float4* __restrict__ o4 = (const float4*)outf;
    int e = blockIdx.x * 16 + (threadIdx.x >> 4);
    int sub = threadIdx.x & 15;
    if (e >= EL) return;
    int a = eli[e], b = eli[EL + e];
    float4 pa = o4[(size_t)a * 16 + sub];
    float4 pb = o4[(size_t)b * 16 + sub];
    float p = pa.x * pb.x + pa.y * pb.y + pa.z * pb.z + pa.w * pb.w;
    for (int off = 8; off; off >>= 1) p += __shfl_xor(p, off, 64);
    if (sub == 0) out[e] = p;
}

extern "C" void kernel_launch(void* const* d_in, const int* in_sizes, int n_in,
                              void* d_out, int out_size, void* d_ws, size_t ws_size,
                              hipStream_t stream)
{
    const float* x      = (const float*)d_in[0];
    const int*   ei     = (const int*)d_in[1];
    const int*   eli    = (const int*)d_in[2];
    const float* Wg     = (const float*)d_in[3];
    const float* att_s  = (const float*)d_in[4];
    const float* att_d  = (const float*)d_in[5];
    const float* bg     = (const float*)d_in[6];
    const float* W1l    = (const float*)d_in[7];
    const float* W1r    = (const float*)d_in[8];
    const float* b1     = (const float*)d_in[9];
    const float* W2l    = (const float*)d_in[10];
    const float* W2r    = (const float*)d_in[11];
    const float* b2     = (const float*)d_in[12];
    const float* alpha  = (const float*)d_in[13];

    const int N  = in_sizes[0] / 11;
    const int E  = in_sizes[1] / 2;
    const int EL = in_sizes[2] / 2;
    const int NBK = (N + 127) >> 7;   // buckets of 128 dsts (<=1024)

    const int* src = ei;
    const int* dst = ei + E;

    // workspace layout
    float* A        = (float*)d_ws;              // N*64: h -> P1 -> P2
    float* B        = A + (size_t)N * 64;        // N*64: h_gat -> Q1/h1 -> Q2
    float* D        = B + (size_t)N * 64;        // N*64: ebuf (CSR build) then output accum
    float* a_src    = D + (size_t)N * 64;        // N
    float* a_dst    = a_src + N;                 // N
    int*   cnt      = (int*)(a_dst + N);         // N
    int*   rowstart = cnt + N;                   // N
    int*   bc       = rowstart + N;              // NBK*16 (padded counters)
    int*   bcur     = bc + NBK * 16;             // NBK*16
    int*   bstart   = bcur + NBK * 16;           // NBK
    int*   csr      = bstart + NBK;              // E
    unsigned short* wf = (unsigned short*)(csr + E);  // 4 x 8192 ushorts
    unsigned short* W1hi = wf;
    unsigned short* W1lo = wf + 8192;
    unsigned short* W2hi = wf + 16384;
    unsigned short* W2lo = wf + 24576;
    float* wsm      = (float*)(wf + 32768);      // 4
    int2*  ebuf     = (int2*)D;                  // E pairs — dead before gat_gather writes D

    hipMemsetAsync(bc, 0, (size_t)NBK * 32 * sizeof(int), stream);  // bc + bcur

    wprep2_kernel<<<8, 256, 0, stream>>>(W1l, W1r, W2l, W2r,
                                         W1hi, W1lo, W2hi, W2lo, alpha, wsm);

    gat_input_kernel<<<(N + 3) / 4, 256, 0, stream>>>(x, Wg, att_s, att_d, A, a_src, a_dst, N);

    // Bucketed CSR build
    bucket_count_kernel<<<(E + 255) / 256, 256, 0, stream>>>(dst, bc, E);
    bucket_scan_kernel<<<1, 1024, 0, stream>>>(bc, bstart, NBK);
    bucket_scatter_kernel<<<(E + 255) / 256, 256, 0, stream>>>(src, dst, bstart, bcur, ebuf, E);
    bucket_build_kernel<<<NBK, 256, 0, stream>>>(ebuf, bstart, bc, cnt, rowstart, csr, N);

    // GAT: read h (A) -> h_gat (B), D = w0*h_gat  (overwrites ebuf — now dead)
    gat_gather_kernel<<<(N + 3) / 4, 256, 0, stream>>>(A, a_src, a_dst, bg,
                                                       rowstart, cnt, csr, wsm, B, D, N);

    // SAGE1: GEMM reads B(hgat): P1 -> A, Q1 -> B (in-place). post: h1 -> B, D += w2*h1
    sage_gemm_kernel<<<(N + 63) / 64, 256, 0, stream>>>(B, W1hi, W1lo, b1, A, B, N);
    sage_post_kernel<<<(N + 3) / 4, 256, 0, stream>>>(A, B, rowstart, cnt, csr, wsm, 2, B, D, N);

    // SAGE2: GEMM reads B(h1): P2 -> A, Q2 -> B (in-place). post: D += w3*h2
    sage_gemm_kernel<<<(N + 63) / 64, 256, 0, stream>>>(B, W2hi, W2lo, b2, A, B, N);
    sage_post_kernel<<<(N + 3) / 4, 256, 0, stream>>>(A, B, rowstart, cnt, csr, wsm, 3, nullptr, D, N);

    link_pred_kernel<<<(EL + 15) / 16, 256, 0, stream>>>(eli, D, (float*)d_out, EL);
}

// Round 8
// 363.426 us; speedup vs baseline: 1.3050x; 1.2494x over previous
//
#include <hip/hip_runtime.h>
#include <math.h>
#include <float.h>

#define NEG_SLOPE 0.2f
#define NCHUNK 128   // edge-array chunks for the deterministic scatter

typedef short short8 __attribute__((ext_vector_type(8)));
typedef float f32x4  __attribute__((ext_vector_type(4)));

__device__ __forceinline__ unsigned short bf16hi(float x) {
    unsigned u = __float_as_uint(x);
    return (unsigned short)((u + 0x7FFFu + ((u >> 16) & 1u)) >> 16);
}
__device__ __forceinline__ float bf16tof(unsigned short h) {
    return __uint_as_float(((unsigned)h) << 16);
}

// K1: h = x @ W_gat  (N x 11 @ 11 x 64), plus a_src = h.att_src, a_dst = h.att_dst
__global__ __launch_bounds__(256) void gat_input_kernel(
    const float* __restrict__ x, const float* __restrict__ Wg,
    const float* __restrict__ att_src, const float* __restrict__ att_dst,
    float* __restrict__ h, float* __restrict__ a_src, float* __restrict__ a_dst, int N)
{
    __shared__ float Wl[11 * 64];
    int tid = threadIdx.x;
    for (int i = tid; i < 11 * 64; i += 256) Wl[i] = Wg[i];
    __syncthreads();
    int lane = tid & 63;
    int n = blockIdx.x * 4 + (tid >> 6);
    if (n >= N) return;
    float acc = 0.f;
    #pragma unroll
    for (int k = 0; k < 11; k++) acc += x[n * 11 + k] * Wl[k * 64 + lane];
    h[(size_t)n * 64 + lane] = acc;
    float ps = acc * att_src[lane];
    float pd = acc * att_dst[lane];
    for (int off = 32; off; off >>= 1) {
        ps += __shfl_down(ps, off, 64);
        pd += __shfl_down(pd, off, 64);
    }
    if (lane == 0) { a_src[n] = ps; a_dst[n] = pd; }
}

// ---- Chunked CSR construction (bucket = dst >> 7; 128 edge-chunks; no global atomics) ----

// block c: LDS histogram of chunk c -> hist[b * NCHUNK + c] (bucket-major)
__global__ __launch_bounds__(1024) void edge_hist_kernel(
    const int* __restrict__ dst, int* __restrict__ hist, int E, int NBK)
{
    __shared__ int c[1024];
    int t = threadIdx.x;
    c[t] = 0;
    __syncthreads();
    int chunk = (E + NCHUNK - 1) / NCHUNK;
    int lo = blockIdx.x * chunk;
    int hi = lo + chunk; if (hi > E) hi = E;
    for (int i = lo + t; i < hi; i += 1024)
        atomicAdd(&c[dst[i] >> 7], 1);
    __syncthreads();
    if (t < NBK) hist[t * NCHUNK + blockIdx.x] = c[t];
}

// block c: scatter chunk c's edges into its exclusive (bucket,chunk) regions; LDS cursors
__global__ __launch_bounds__(1024) void edge_scatter_kernel(
    const int* __restrict__ src, const int* __restrict__ dst,
    const int* __restrict__ rstart, int2* __restrict__ ebuf, int E, int NBK)
{
    __shared__ int cur[1024];
    int t = threadIdx.x;
    if (t < NBK) cur[t] = rstart[t * NCHUNK + blockIdx.x];
    __syncthreads();
    int chunk = (E + NCHUNK - 1) / NCHUNK;
    int lo = blockIdx.x * chunk;
    int hi = lo + chunk; if (hi > E) hi = E;
    for (int i = lo + t; i < hi; i += 1024) {
        int d = dst[i];
        int p = atomicAdd(&cur[d >> 7], 1);
        ebuf[p] = make_int2(src[i], d);
    }
}

// ---- generic exclusive scan (M elements, M <= 256*1024) ----
__global__ __launch_bounds__(256) void scan_reduce_kernel(
    const int* __restrict__ v, int* __restrict__ bsum, int M)
{
    __shared__ int s[256];
    int t = threadIdx.x;
    int base = blockIdx.x * 1024 + t * 4;
    int sum = 0;
    #pragma unroll
    for (int j = 0; j < 4; j++) { int idx = base + j; if (idx < M) sum += v[idx]; }
    s[t] = sum; __syncthreads();
    for (int off = 128; off; off >>= 1) {
        if (t < off) s[t] += s[t + off];
        __syncthreads();
    }
    if (t == 0) bsum[blockIdx.x] = s[0];
}

__global__ __launch_bounds__(256) void scan_spine_kernel(
    const int* __restrict__ bsum, int* __restrict__ boff, int NB)
{
    __shared__ int s[256];
    int t = threadIdx.x;
    int v = (t < NB) ? bsum[t] : 0;
    s[t] = v; __syncthreads();
    for (int off = 1; off < 256; off <<= 1) {
        int x = (t >= off) ? s[t - off] : 0;
        __syncthreads();
        s[t] += x;
        __syncthreads();
    }
    if (t < NB) boff[t] = s[t] - v;
}

__global__ __launch_bounds__(256) void scan_apply_kernel(
    const int* __restrict__ v, const int* __restrict__ boff,
    int* __restrict__ out, int M)
{
    __shared__ int s[256];
    int t = threadIdx.x;
    int base = blockIdx.x * 1024;
    int vv[4]; int sum = 0;
    #pragma unroll
    for (int j = 0; j < 4; j++) {
        int idx = base + t * 4 + j;
        vv[j] = (idx < M) ? v[idx] : 0;
        sum += vv[j];
    }
    s[t] = sum; __syncthreads();
    for (int off = 1; off < 256; off <<= 1) {
        int x = (t >= off) ? s[t - off] : 0;
        __syncthreads();
        s[t] += x;
        __syncthreads();
    }
    int ex = s[t] - sum + boff[blockIdx.x];
    #pragma unroll
    for (int j = 0; j < 4; j++) {
        int idx = base + t * 4 + j;
        if (idx < M) out[idx] = ex;
        ex += vv[j];
    }
}

// one workgroup per bucket: LDS per-dst counts -> LDS scan -> cnt/rowstart -> scatter csr
__global__ __launch_bounds__(256) void bucket_build_kernel(
    const int2* __restrict__ ebuf, const int* __restrict__ rstart,
    int* __restrict__ cnt, int* __restrict__ rowstart,
    int* __restrict__ csr, int E, int N, int NBK)
{
    __shared__ int c[128];
    __shared__ int rs[128];
    __shared__ int cur[128];
    int b = blockIdx.x, t = threadIdx.x;
    if (t < 128) { c[t] = 0; cur[t] = 0; }
    __syncthreads();
    int beg = rstart[b * NCHUNK];
    int end = (b == NBK - 1) ? E : rstart[(b + 1) * NCHUNK];
    int n = end - beg;
    for (int j = t; j < n; j += 256)
        atomicAdd(&c[ebuf[beg + j].y & 127], 1);
    __syncthreads();
    int myc = (t < 128) ? c[t] : 0;
    if (t < 128) rs[t] = myc;
    __syncthreads();
    for (int off = 1; off < 128; off <<= 1) {
        int v = (t < 128 && t >= off) ? rs[t - off] : 0;
        __syncthreads();
        if (t < 128) rs[t] += v;
        __syncthreads();
    }
    int ex = (t < 128) ? (rs[t] - myc) : 0;
    __syncthreads();
    if (t < 128) rs[t] = ex;
    int base = b << 7;
    if (t < 128 && base + t < N) {
        cnt[base + t] = myc;
        rowstart[base + t] = beg + ex;
    }
    __syncthreads();
    for (int j = t; j < n; j += 256) {
        int2 e = ebuf[beg + j];
        int d = e.y & 127;
        int p = atomicAdd(&cur[d], 1);
        csr[beg + rs[d] + p] = e.x;
    }
}

// K2: GAT gather — wave per dst node, plain exp softmax (logits bounded), float4 gathers
__global__ __launch_bounds__(256) void gat_gather_kernel(
    const float* __restrict__ h, const float* __restrict__ a_src,
    const float* __restrict__ a_dst, const float* __restrict__ bg,
    const int* __restrict__ rowstart, const int* __restrict__ cnt,
    const int* __restrict__ csr, const float* __restrict__ wsm,
    float* __restrict__ hgat, float* __restrict__ outD, int N)
{
    const float4* __restrict__ h4 = (const float4*)h;
    int d = blockIdx.x * 4 + (threadIdx.x >> 6);
    int lane = threadIdx.x & 63;
    if (d >= N) return;
    int grp = lane >> 4;
    int sub = lane & 15;
    float ad = a_dst[d];
    int beg = rowstart[d], deg = cnt[d];
    float a0 = a_src[d] + ad;
    float lg0 = a0 > 0.f ? a0 : NEG_SLOPE * a0;
    float w_self = expf(lg0);
    float l_lane = 0.f;
    float4 accA = make_float4(0.f, 0.f, 0.f, 0.f);
    float4 accB = make_float4(0.f, 0.f, 0.f, 0.f);
    if (grp == 0) {
        float4 hv = h4[(size_t)d * 16 + sub];
        accA.x = w_self * hv.x; accA.y = w_self * hv.y;
        accA.z = w_self * hv.z; accA.w = w_self * hv.w;
    }
    for (int base = 0; base < deg; base += 64) {
        int eidx = base + lane;
        bool valid = eidx < deg;
        int sid = valid ? csr[beg + eidx] : 0;
        float aa = a_src[sid] + ad;
        float lg = aa > 0.f ? aa : NEG_SLOPE * aa;
        float w = valid ? expf(lg) : 0.f;
        l_lane += w;
        int nvalid = deg - base; if (nvalid > 64) nvalid = 64;
        for (int j = 0; j < nvalid; j += 16) {
            int e0 = j + grp,      e1 = j + 4 + grp;
            int e2 = j + 8 + grp,  e3 = j + 12 + grp;
            int   i0 = __shfl(sid, e0, 64); float w0 = __shfl(w, e0, 64);
            int   i1 = __shfl(sid, e1, 64); float w1 = __shfl(w, e1, 64);
            int   i2 = __shfl(sid, e2, 64); float w2 = __shfl(w, e2, 64);
            int   i3 = __shfl(sid, e3, 64); float w3 = __shfl(w, e3, 64);
            float4 v0 = h4[(size_t)i0 * 16 + sub];
            float4 v1 = h4[(size_t)i1 * 16 + sub];
            float4 v2 = h4[(size_t)i2 * 16 + sub];
            float4 v3 = h4[(size_t)i3 * 16 + sub];
            accA.x += w0 * v0.x + w1 * v1.x; accB.x += w2 * v2.x + w3 * v3.x;
            accA.y += w0 * v0.y + w1 * v1.y; accB.y += w2 * v2.y + w3 * v3.y;
            accA.z += w0 * v0.z + w1 * v1.z; accB.z += w2 * v2.z + w3 * v3.z;
            accA.w += w0 * v0.w + w1 * v1.w; accB.w += w2 * v2.w + w3 * v3.w;
        }
    }
    for (int off = 32; off; off >>= 1) l_lane += __shfl_xor(l_lane, off, 64);
    float l = l_lane + w_self;
    float4 acc;
    acc.x = accA.x + accB.x; acc.y = accA.y + accB.y;
    acc.z = accA.z + accB.z; acc.w = accA.w + accB.w;
    #pragma unroll
    for (int off = 16; off <= 32; off <<= 1) {
        acc.x += __shfl_xor(acc.x, off, 64);
        acc.y += __shfl_xor(acc.y, off, 64);
        acc.z += __shfl_xor(acc.z, off, 64);
        acc.w += __shfl_xor(acc.w, off, 64);
    }
    float inv = 1.0f / (l + 1e-16f);
    const float4* bg4 = (const float4*)bg;
    float4 bb = bg4[sub];
    float4 out;
    out.x = acc.x * inv + bb.x; out.y = acc.y * inv + bb.y;
    out.z = acc.z * inv + bb.z; out.w = acc.w * inv + bb.w;
    size_t idx = (size_t)d * 16 + sub;
    if (grp == 0) ((float4*)hgat)[idx] = out;
    if (grp == 1) {
        float w0 = wsm[0];
        float4 o; o.x = w0 * out.x; o.y = w0 * out.y; o.z = w0 * out.z; o.w = w0 * out.w;
        ((float4*)outD)[idx] = o;
    }
}

// K5: both weight pairs -> MFMA b-frag layout (bf16 hi/lo); block 0 also does softmax(alpha).
__global__ __launch_bounds__(256) void wprep2_kernel(
    const float* __restrict__ W1l, const float* __restrict__ W1r,
    const float* __restrict__ W2l, const float* __restrict__ W2r,
    unsigned short* __restrict__ W1hi, unsigned short* __restrict__ W1lo,
    unsigned short* __restrict__ W2hi, unsigned short* __restrict__ W2lo,
    const float* __restrict__ alpha, float* __restrict__ wsm)
{
    if (blockIdx.x == 0 && threadIdx.x == 0) {
        float m = alpha[0];
        for (int i = 1; i < 4; i++) m = fmaxf(m, alpha[i]);
        float e[4], s = 0.f;
        for (int i = 0; i < 4; i++) { e[i] = expf(alpha[i] - m); s += e[i]; }
        for (int i = 0; i < 4; i++) wsm[i] = e[i] / s;
    }
    int which = blockIdx.x >> 2;
    const float* Wl = which ? W2l : W1l;
    const float* Wr = which ? W2r : W1r;
    unsigned short* Whi = which ? W2hi : W1hi;
    unsigned short* Wlo = which ? W2lo : W1lo;
    int idx = (blockIdx.x & 3) * 256 + threadIdx.x;   // 0..1023
    int kc = idx >> 9, rem = idx & 511;
    int t = rem >> 6, lane = rem & 63;
    int quad = lane >> 4, col16 = lane & 15;
    int c = t * 16 + col16;
    #pragma unroll
    for (int j = 0; j < 8; j++) {
        int k = kc * 32 + quad * 8 + j;
        float w = (c < 64) ? Wl[k * 64 + c] : Wr[k * 64 + (c - 64)];
        unsigned short hi = bf16hi(w);
        unsigned short lo = bf16hi(w - bf16tof(hi));
        Whi[(size_t)idx * 8 + j] = hi;
        Wlo[(size_t)idx * 8 + j] = lo;
    }
}

// K6: dense GEMM [P|Q] = hin @ [Wl|Wr] (+b on Q half) via mfma 16x16x32 bf16x3.
__global__ __launch_bounds__(256) void sage_gemm_kernel(
    const float* __restrict__ hin,
    const unsigned short* __restrict__ Whi, const unsigned short* __restrict__ Wlo,
    const float* __restrict__ bvec,
    float* __restrict__ P, float* __restrict__ Q, int N)
{
    int wave = threadIdx.x >> 6, lane = threadIdx.x & 63;
    int base = blockIdx.x * 64 + wave * 16;
    if (base >= N) return;
    int quad = lane >> 4, col16 = lane & 15;
    int m = base + col16;
    int mc = m < N ? m : N - 1;
    f32x4 acc[8];
    #pragma unroll
    for (int t = 0; t < 8; t++) acc[t] = (f32x4){0.f, 0.f, 0.f, 0.f};
    #pragma unroll
    for (int kc = 0; kc < 2; kc++) {
        const float* ap = hin + (size_t)mc * 64 + kc * 32 + quad * 8;
        float4 va = *(const float4*)ap;
        float4 vb = *(const float4*)(ap + 4);
        float av[8] = {va.x, va.y, va.z, va.w, vb.x, vb.y, vb.z, vb.w};
        short8 ahi, alo;
        #pragma unroll
        for (int j = 0; j < 8; j++) {
            unsigned short hh = bf16hi(av[j]);
            ahi[j] = (short)hh;
            alo[j] = (short)bf16hi(av[j] - bf16tof(hh));
        }
        #pragma unroll
        for (int t = 0; t < 8; t++) {
            size_t off = ((size_t)(kc * 8 + t) * 64 + lane) * 8;
            short8 bhi = *(const short8*)(Whi + off);
            short8 blo = *(const short8*)(Wlo + off);
            acc[t] = __builtin_amdgcn_mfma_f32_16x16x32_bf16(ahi, bhi, acc[t], 0, 0, 0);
            acc[t] = __builtin_amdgcn_mfma_f32_16x16x32_bf16(alo, bhi, acc[t], 0, 0, 0);
            acc[t] = __builtin_amdgcn_mfma_f32_16x16x32_bf16(ahi, blo, acc[t], 0, 0, 0);
        }
    }
    #pragma unroll
    for (int t = 0; t < 8; t++) {
        #pragma unroll
        for (int r = 0; r < 4; r++) {
            int node = base + quad * 4 + r;
            if (node < N) {
                float v = acc[t][r];
                if (t < 4) {
                    P[(size_t)node * 64 + t * 16 + col16] = v;
                } else {
                    int c = (t - 4) * 16 + col16;
                    Q[(size_t)node * 64 + c] = v + bvec[c];
                }
            }
        }
    }
}

// K7: SAGE post — h' = mean_nbr(P) + Q[d]; outD += w*h'; optional hout store.
__global__ __launch_bounds__(256) void sage_post_kernel(
    const float* __restrict__ P, const float* __restrict__ Q,
    const int* __restrict__ rowstart, const int* __restrict__ cnt,
    const int* __restrict__ csr, const float* __restrict__ wsm, int widx,
    float* __restrict__ hout, float* __restrict__ outD, int N)
{
    const float4* __restrict__ P4 = (const float4*)P;
    int d = blockIdx.x * 4 + (threadIdx.x >> 6);
    int lane = threadIdx.x & 63;
    if (d >= N) return;
    int grp = lane >> 4, sub = lane & 15;
    int beg = rowstart[d], deg = cnt[d];
    float4 s0 = make_float4(0.f,0.f,0.f,0.f), s1 = s0, s2 = s0, s3 = s0;
    for (int base = 0; base < deg; base += 64) {
        int nv = deg - base; if (nv > 64) nv = 64;
        int sid = (lane < nv) ? csr[beg + base + lane] : 0;
        for (int j = 0; j < nv; j += 16) {
            int e0 = j + grp,     e1 = j + 4 + grp;
            int e2 = j + 8 + grp, e3 = j + 12 + grp;
            int i0 = __shfl(sid, e0, 64);
            int i1 = __shfl(sid, e1, 64);
            int i2 = __shfl(sid, e2, 64);
            int i3 = __shfl(sid, e3, 64);
            if (e0 < nv) { float4 v = P4[(size_t)i0 * 16 + sub]; s0.x += v.x; s0.y += v.y; s0.z += v.z; s0.w += v.w; }
            if (e1 < nv) { float4 v = P4[(size_t)i1 * 16 + sub]; s1.x += v.x; s1.y += v.y; s1.z += v.z; s1.w += v.w; }
            if (e2 < nv) { float4 v = P4[(size_t)i2 * 16 + sub]; s2.x += v.x; s2.y += v.y; s2.z += v.z; s2.w += v.w; }
            if (e3 < nv) { float4 v = P4[(size_t)i3 * 16 + sub]; s3.x += v.x; s3.y += v.y; s3.z += v.z; s3.w += v.w; }
        }
    }
    float4 sv;
    sv.x = (s0.x + s1.x) + (s2.x + s3.x);
    sv.y = (s0.y + s1.y) + (s2.y + s3.y);
    sv.z = (s0.z + s1.z) + (s2.z + s3.z);
    sv.w = (s0.w + s1.w) + (s2.w + s3.w);
    #pragma unroll
    for (int off = 16; off <= 32; off <<= 1) {
        sv.x += __shfl_xor(sv.x, off, 64);
        sv.y += __shfl_xor(sv.y, off, 64);
        sv.z += __shfl_xor(sv.z, off, 64);
        sv.w += __shfl_xor(sv.w, off, 64);
    }
    float invd = 1.0f / fmaxf((float)deg, 1.0f);
    size_t idx = (size_t)d * 16 + sub;
    float4 q4 = ((const float4*)Q)[idx];
    float4 o;
    o.x = sv.x * invd + q4.x; o.y = sv.y * invd + q4.y;
    o.z = sv.z * invd + q4.z; o.w = sv.w * invd + q4.w;
    if (hout && grp == 0) ((float4*)hout)[idx] = o;
    if (grp == 1) {
        float w = wsm[widx];
        float4 dd = ((float4*)outD)[idx];
        dd.x += w * o.x; dd.y += w * o.y; dd.z += w * o.z; dd.w += w * o.w;
        ((float4*)outD)[idx] = dd;
    }
}

// K8: 16 lanes per label-edge (float4 rows): out[e] = dot(outf[a], outf[b])
__global__ __launch_bounds__(256) void link_pred_kernel(
    const int* __restrict__ eli, const float* __restrict__ outf,
    float* __restrict__ out, int EL)
{
    const float4* __restrict__ o4 = (const float4*)outf;
    int e = blockIdx.x * 16 + (threadIdx.x >> 4);
    int sub = threadIdx.x & 15;
    if (e >= EL) return;
    int a = eli[e], b = eli[EL + e];
    float4 pa = o4[(size_t)a * 16 + sub];
    float4 pb = o4[(size_t)b * 16 + sub];
    float p = pa.x * pb.x + pa.y * pb.y + pa.z * pb.z + pa.w * pb.w;
    for (int off = 8; off; off >>= 1) p += __shfl_xor(p, off, 64);
    if (sub == 0) out[e] = p;
}

extern "C" void kernel_launch(void* const* d_in, const int* in_sizes, int n_in,
                              void* d_out, int out_size, void* d_ws, size_t ws_size,
                              hipStream_t stream)
{
    const float* x      = (const float*)d_in[0];
    const int*   ei     = (const int*)d_in[1];
    const int*   eli    = (const int*)d_in[2];
    const float* Wg     = (const float*)d_in[3];
    const float* att_s  = (const float*)d_in[4];
    const float* att_d  = (const float*)d_in[5];
    const float* bg     = (const float*)d_in[6];
    const float* W1l    = (const float*)d_in[7];
    const float* W1r    = (const float*)d_in[8];
    const float* b1     = (const float*)d_in[9];
    const float* W2l    = (const float*)d_in[10];
    const float* W2r    = (const float*)d_in[11];
    const float* b2     = (const float*)d_in[12];
    const float* alpha  = (const float*)d_in[13];

    const int N  = in_sizes[0] / 11;
    const int E  = in_sizes[1] / 2;
    const int EL = in_sizes[2] / 2;
    const int NBK = (N + 127) >> 7;      // buckets of 128 dsts (782 for N=100k, <=1024)
    const int M   = NBK * NCHUNK;        // hist/rstart table size

    const int* src = ei;
    const int* dst = ei + E;

    // workspace layout
    float* A        = (float*)d_ws;              // N*64: h -> P1 -> P2
    float* B        = A + (size_t)N * 64;        // N*64: h_gat -> Q1/h1 -> Q2
    float* D        = B + (size_t)N * 64;        // N*64: ebuf (CSR build) then output accum
    float* a_src    = D + (size_t)N * 64;        // N
    float* a_dst    = a_src + N;                 // N
    int*   cnt      = (int*)(a_dst + N);         // N
    int*   rowstart = cnt + N;                   // N
    int*   hist     = rowstart + N;              // M  (bucket-major: [b*NCHUNK + c])
    int*   rstart   = hist + M;                  // M  (exclusive scan of hist)
    int*   bsum     = rstart + M;                // 256
    int*   boff     = bsum + 256;                // 256
    int*   csr      = boff + 256;                // E
    unsigned short* wf = (unsigned short*)(csr + E);  // 4 x 8192 ushorts
    unsigned short* W1hi = wf;
    unsigned short* W1lo = wf + 8192;
    unsigned short* W2hi = wf + 16384;
    unsigned short* W2lo = wf + 24576;
    float* wsm      = (float*)(wf + 32768);      // 4
    int2*  ebuf     = (int2*)D;                  // E pairs — dead before gat_gather writes D

    wprep2_kernel<<<8, 256, 0, stream>>>(W1l, W1r, W2l, W2r,
                                         W1hi, W1lo, W2hi, W2lo, alpha, wsm);

    gat_input_kernel<<<(N + 3) / 4, 256, 0, stream>>>(x, Wg, att_s, att_d, A, a_src, a_dst, N);

    // Chunked CSR build (no global atomics, XCD-local writes)
    edge_hist_kernel<<<NCHUNK, 1024, 0, stream>>>(dst, hist, E, NBK);
    int NB = (M + 1023) / 1024;   // 98 for M=100096
    scan_reduce_kernel<<<NB, 256, 0, stream>>>(hist, bsum, M);
    scan_spine_kernel<<<1, 256, 0, stream>>>(bsum, boff, NB);
    scan_apply_kernel<<<NB, 256, 0, stream>>>(hist, boff, rstart, M);
    edge_scatter_kernel<<<NCHUNK, 1024, 0, stream>>>(src, dst, rstart, ebuf, E, NBK);
    bucket_build_kernel<<<NBK, 256, 0, stream>>>(ebuf, rstart, cnt, rowstart, csr, E, N, NBK);

    // GAT: read h (A) -> h_gat (B), D = w0*h_gat  (overwrites ebuf — now dead)
    gat_gather_kernel<<<(N + 3) / 4, 256, 0, stream>>>(A, a_src, a_dst, bg,
                                                       rowstart, cnt, csr, wsm, B, D, N);

    // SAGE1: GEMM reads B(hgat): P1 -> A, Q1 -> B (in-place). post: h1 -> B, D += w2*h1
    sage_gemm_kernel<<<(N + 63) / 64, 256, 0, stream>>>(B, W1hi, W1lo, b1, A, B, N);
    sage_post_kernel<<<(N + 3) / 4, 256, 0, stream>>>(A, B, rowstart, cnt, csr, wsm, 2, B, D, N);

    // SAGE2: GEMM reads B(h1): P2 -> A, Q2 -> B (in-place). post: D += w3*h2
    sage_gemm_kernel<<<(N + 63) / 64, 256, 0, stream>>>(B, W2hi, W2lo, b2, A, B, N);
    sage_post_kernel<<<(N + 3) / 4, 256, 0, stream>>>(A, B, rowstart, cnt, csr, wsm, 3, nullptr, D, N);

    link_pred_kernel<<<(EL + 15) / 16, 256, 0, stream>>>(eli, D, (float*)d_out, EL);
}